// Round 1
// baseline (3419.943 us; speedup 1.0000x reference)
//
#include <hip/hip_runtime.h>
#include <hip/hip_bf16.h>

// Biaffine: out[b,x,y,o] = bwn0 * sum_{i,j} x1b[b,x,i] W_bil[o,i,j] x2b[b,y,j]
//                        + bwn1 * (lin1[b,x,o] + lin2[b,y,o] + b_lin[o])
// Factorization:
//   lin1pb[bx,o] = x1[bx,:] @ W_lin[:512,o] + b_lin[o]
//   T'[x,o,j]    = bwn0*(x1b[bx,:] @ W_bil[o,:,j]) + bwn1*W_lin[512+j,o]   (j<512)
//   T'[x,o,512]  = bwn0*(...) + bwn1*lin1pb[bx,o]
//   out[b,x,y,o] = sum_j x2b[b,y,j] * T'[x,o,j]      (exactly the final output)
// T' stored bf16, one batch at a time (ws = 0.5MB + ~33MB).

#define BB 4
#define LL 256
#define DD 512
#define OO 128
#define KD 513      // D+1 (with bias column)
#define JP 520      // padded j-stride of T' (multiple of 8, breaks 512 aliasing)

__global__ __launch_bounds__(128) void lin1_kernel(
    const float* __restrict__ x1, const float* __restrict__ W_lin,
    const float* __restrict__ b_lin, float* __restrict__ lin1pb)
{
    __shared__ float xs[DD];
    const int bx = blockIdx.x;       // 0..1023 (b*L + x)
    const int o  = threadIdx.x;      // 0..127
    const float* xr = x1 + (size_t)bx * DD;
    for (int i = o; i < DD; i += 128) xs[i] = xr[i];
    __syncthreads();
    float s = b_lin[o];
    for (int i = 0; i < DD; ++i) s += xs[i] * W_lin[(size_t)i * OO + o];
    lin1pb[(size_t)bx * OO + o] = s;
}

// Pass 1: per batch b. C-tile 64(x) x 64(j) per block, K = 513 (i, incl bias row).
// grid (9 j-tiles, 4 x-tiles, 128 o), block (16,16).
__global__ __launch_bounds__(256) void pass1_kernel(
    const float* __restrict__ x1, const float* __restrict__ W_bil,
    const float* __restrict__ W_lin, const float* __restrict__ lin1pb,
    const float* __restrict__ bw, __hip_bfloat16* __restrict__ Tp, int b)
{
    __shared__ float As[16][68];   // [k][x]
    __shared__ float Bs[16][68];   // [k][j]
    const int tx = threadIdx.x, ty = threadIdx.y;
    const int t  = ty * 16 + tx;
    const int j0 = blockIdx.x * 64;
    const int x0 = blockIdx.y * 64;
    const int o  = blockIdx.z;

    const float e0 = __expf(bw[0]), e1 = __expf(bw[1]);
    const float bwn0 = e0 / (e0 + e1), bwn1 = e1 / (e0 + e1);

    float acc[4][4] = {};
    const float* Wo = W_bil + (size_t)o * KD * KD;

    for (int kt = 0; kt < 33; ++kt) {       // 33*16 = 528 >= 513
        const int k0 = kt * 16;
        // A-tile: 64 x (x) * 16 (i); x1b has ones at i==512
        #pragma unroll
        for (int q = 0; q < 4; ++q) {
            int r  = t + 256 * q;
            int xx = r >> 4;
            int ii = r & 15;
            int ig = k0 + ii;
            float v;
            if (ig < DD)      v = x1[((size_t)(b * LL + x0 + xx)) * DD + ig];
            else              v = (ig == DD) ? 1.0f : 0.0f;
            As[ii][xx] = v;
        }
        // B-tile: 16 (i) * 64 (j) from W_bil[o]
        #pragma unroll
        for (int q = 0; q < 4; ++q) {
            int r  = t + 256 * q;
            int jj = r & 63;
            int ii = r >> 6;
            int ig = k0 + ii;
            int jg = j0 + jj;
            float v = 0.0f;
            if (ig < KD && jg < KD) v = Wo[(size_t)ig * KD + jg];
            Bs[ii][jj] = v;
        }
        __syncthreads();
        #pragma unroll
        for (int k = 0; k < 16; ++k) {
            float a[4], bb[4];
            #pragma unroll
            for (int e = 0; e < 4; ++e) a[e] = As[k][ty * 4 + e];
            #pragma unroll
            for (int f = 0; f < 4; ++f) bb[f] = Bs[k][tx * 4 + f];
            #pragma unroll
            for (int e = 0; e < 4; ++e)
                #pragma unroll
                for (int f = 0; f < 4; ++f)
                    acc[e][f] += a[e] * bb[f];
        }
        __syncthreads();
    }

    // Epilogue: fold linear path, scale by softmax weights, store bf16.
    #pragma unroll
    for (int e = 0; e < 4; ++e) {
        const int x = x0 + ty * 4 + e;
        #pragma unroll
        for (int f = 0; f < 4; ++f) {
            const int j = j0 + tx * 4 + f;
            if (j < KD) {
                float add = (j < DD)
                    ? bwn1 * W_lin[(size_t)(DD + j) * OO + o]
                    : bwn1 * lin1pb[(size_t)(b * LL + x) * OO + o];
                float val = bwn0 * acc[e][f] + add;
                Tp[((size_t)x * OO + o) * JP + j] = __float2bfloat16(val);
            }
        }
    }
}

// Pass 2: per batch b. For fixed x: out[b,x,:,:] (256 y x 128 o, contiguous)
//   = x2b[b] (256 x 513) @ T'[x] (513 x 128, stored o-major rows of JP).
// grid (4 y-tiles, 256 x), block (16,16); C-tile 64(y) x 128(o), acc 4x8.
__global__ __launch_bounds__(256) void pass2_kernel(
    const float* __restrict__ x2, const float* __restrict__ bw,
    const __hip_bfloat16* __restrict__ Tp, float* __restrict__ out, int b)
{
    __shared__ float As[16][68];    // [k][y]
    __shared__ float Bs[16][132];   // [k][o]
    const int tx = threadIdx.x, ty = threadIdx.y;
    const int t  = ty * 16 + tx;
    const int y0 = blockIdx.x * 64;
    const int x  = blockIdx.y;

    float acc[4][8] = {};

    for (int kt = 0; kt < 33; ++kt) {
        const int k0 = kt * 16;
        // A-tile: 64 (y) x 16 (j); x2b ones at j==512
        #pragma unroll
        for (int q = 0; q < 4; ++q) {
            int r  = t + 256 * q;
            int yy = r >> 4;
            int jj = r & 15;
            int j  = k0 + jj;
            float v;
            if (j < DD)      v = x2[((size_t)(b * LL + y0 + yy)) * DD + j];
            else             v = (j == DD) ? 1.0f : 0.0f;
            As[jj][yy] = v;
        }
        // B-tile: 16 (j) x 128 (o) gathered from T' o-major rows
        #pragma unroll
        for (int q = 0; q < 8; ++q) {
            int r  = t + 256 * q;
            int oo = r >> 4;
            int jj = r & 15;
            int j  = k0 + jj;
            float v = 0.0f;
            if (j < KD) v = __bfloat162float(Tp[((size_t)x * OO + oo) * JP + j]);
            Bs[jj][oo] = v;
        }
        __syncthreads();
        #pragma unroll
        for (int k = 0; k < 16; ++k) {
            float a[4], bb[8];
            #pragma unroll
            for (int e = 0; e < 4; ++e) a[e] = As[k][ty * 4 + e];
            #pragma unroll
            for (int f = 0; f < 8; ++f) bb[f] = Bs[k][tx * 8 + f];
            #pragma unroll
            for (int e = 0; e < 4; ++e)
                #pragma unroll
                for (int f = 0; f < 8; ++f)
                    acc[e][f] += a[e] * bb[f];
        }
        __syncthreads();
    }

    #pragma unroll
    for (int e = 0; e < 4; ++e) {
        const int y = y0 + ty * 4 + e;
        float* orow = out + (((size_t)(b * LL + x)) * LL + y) * OO;
        #pragma unroll
        for (int f = 0; f < 8; ++f)
            orow[tx * 8 + f] = acc[e][f];
    }
}

extern "C" void kernel_launch(void* const* d_in, const int* in_sizes, int n_in,
                              void* d_out, int out_size, void* d_ws, size_t ws_size,
                              hipStream_t stream)
{
    const float* x1    = (const float*)d_in[0];   // [4,256,512]
    const float* x2    = (const float*)d_in[1];   // [4,256,512]
    const float* bw    = (const float*)d_in[2];   // [2]
    const float* W_bil = (const float*)d_in[3];   // [128,513,513]
    const float* W_lin = (const float*)d_in[4];   // [1024,128]
    const float* b_lin = (const float*)d_in[5];   // [128]
    float* out = (float*)d_out;

    float* lin1pb = (float*)d_ws;                                   // 1024*128 fp32 = 512 KB
    __hip_bfloat16* Tp = (__hip_bfloat16*)((char*)d_ws + (size_t)(BB * LL * OO) * 4);
    // Tp: 256*128*520*2 ~= 33 MB (per-batch, reused)

    lin1_kernel<<<BB * LL, 128, 0, stream>>>(x1, W_lin, b_lin, lin1pb);

    for (int b = 0; b < BB; ++b) {
        pass1_kernel<<<dim3(9, 4, OO), dim3(16, 16), 0, stream>>>(
            x1, W_bil, W_lin, lin1pb, bw, Tp, b);
        pass2_kernel<<<dim3(4, LL), dim3(16, 16), 0, stream>>>(
            x2, bw, Tp, out, b);
    }
}

// Round 2
// 609.357 us; speedup vs baseline: 5.6124x; 5.6124x over previous
//
#include <hip/hip_runtime.h>

// Biaffine via right-to-left association (both GEMMs K-contiguous, MFMA bf16):
//   lin2pb[by,o]  = x2[by,:] @ W_lin[512:,o] + b_lin[o]                  (fp32)
//   u512[y,o]     = bwn0*(sum_j W_bil[o,512,j] x2b[y,j]) + bwn1*lin2pb   (fp32)
//   U'[y,o,i]     = bwn0*(sum_{j<512} W_bil[o,i,j] x2b[y,j] + W_bil[o,i,512])
//                 + bwn1*W_lin[i,o]                                      (bf16, i<512)
//   out[b,x,y,o]  = sum_{i<512} x1b16[x,i]*U'[y,o,i] + u512[y,o]         (fp32)
// Per-batch U' (33.5 MB) keeps ws ~36 MB.

#define LL 256
#define DD 512
#define OO 128
#define WB_OI 263169   // 513*513
#define WB_R512 262656 // 512*513

typedef __attribute__((ext_vector_type(8))) short  short8;
typedef __attribute__((ext_vector_type(8))) unsigned short us8;
typedef __attribute__((ext_vector_type(4))) unsigned short us4;
typedef __attribute__((ext_vector_type(4))) float  f32x4;

__device__ __forceinline__ unsigned short f2bf(float f) {
    unsigned int u = __builtin_bit_cast(unsigned int, f);
    u = (u + 0x7FFFu + ((u >> 16) & 1u)) >> 16;
    return (unsigned short)u;
}
__device__ __forceinline__ float bf2f(unsigned short s) {
    return __builtin_bit_cast(float, (unsigned int)s << 16);
}
__device__ __forceinline__ void load_lds16(const void* g, void* l) {
    __builtin_amdgcn_global_load_lds(
        (const __attribute__((address_space(1))) unsigned int*)g,
        (__attribute__((address_space(3))) unsigned int*)l, 16, 0, 0);
}

// ---- cast fp32 -> bf16 (x1, x2), 4 elems/thread ----
__global__ __launch_bounds__(256) void cast_kernel(
    const float* __restrict__ src, unsigned short* __restrict__ dst, int n4)
{
    int i = blockIdx.x * 256 + threadIdx.x;
    if (i < n4) {
        float4 v = ((const float4*)src)[i];
        us4 u; u.x = f2bf(v.x); u.y = f2bf(v.y); u.z = f2bf(v.z); u.w = f2bf(v.w);
        *(us4*)(dst + (size_t)i * 4) = u;
    }
}

// ---- lin2pb[by,o] = b_lin[o] + sum_j x2[by,j]*W_lin[512+j, o] ----
__global__ __launch_bounds__(128) void lin2_kernel(
    const float* __restrict__ x2, const float* __restrict__ W_lin,
    const float* __restrict__ b_lin, float* __restrict__ lin2pb)
{
    __shared__ float xs[DD];
    const int by = blockIdx.x, o = threadIdx.x;
    const float* xr = x2 + (size_t)by * DD;
    for (int j = o; j < DD; j += 128) xs[j] = xr[j];
    __syncthreads();
    float s = b_lin[o];
    for (int j = 0; j < DD; ++j) s += xs[j] * W_lin[(size_t)(DD + j) * OO + o];
    lin2pb[(size_t)by * OO + o] = s;
}

// ---- u512[y,o] for batch b ----
__global__ __launch_bounds__(128) void u512_kernel(
    const float* __restrict__ x2, const float* __restrict__ W_bil,
    const float* __restrict__ lin2pb, const float* __restrict__ bw,
    float* __restrict__ u512buf, int b)
{
    __shared__ float xs[DD];
    const int y = blockIdx.x, o = threadIdx.x;
    const float* xr = x2 + (size_t)(b * LL + y) * DD;
    for (int j = o; j < DD; j += 128) xs[j] = xr[j];
    __syncthreads();
    const float* W2 = W_bil + (size_t)o * WB_OI + WB_R512;
    float s = W2[512];                        // j=512 term (x2b ones col)
    for (int j = 0; j < DD; ++j) s += xs[j] * W2[j];
    float e0 = __expf(bw[0]), e1 = __expf(bw[1]);
    float bwn0 = e0 / (e0 + e1), bwn1 = e1 / (e0 + e1);
    u512buf[y * OO + o] = bwn0 * s + bwn1 * lin2pb[(size_t)(b * LL + y) * OO + o];
}

// ---- pass A: U'[y,o,i] = bwn0*(x2b W^T) + corr, 128x128 tile MFMA ----
// grid (i-tile 4, y-tile 2, o 128), block 256 (4 waves, 2x2)
__global__ __launch_bounds__(256) void passA_kernel(
    const unsigned short* __restrict__ x2b, const float* __restrict__ W_bil,
    const float* __restrict__ W_lin, const float* __restrict__ bw,
    unsigned short* __restrict__ Up, int b)
{
    __shared__ char smem[34816 + 512];
    unsigned short* As = (unsigned short*)smem;            // [128 y][32 j] 8KB
    unsigned short* Bs = (unsigned short*)(smem + 8192);   // [128 i][40] 10KB (pad)
    unsigned short* Cs = (unsigned short*)smem;            // [128 y][136] 34816B (reuse)
    float* corr = (float*)(smem + 34816);                  // [128]

    const int t = threadIdx.x, w = t >> 6, l = t & 63;
    const int ib = blockIdx.x * 128;
    const int yb = blockIdx.y * 128;
    const int o  = blockIdx.z;
    const int wy = w & 1, wx = w >> 1;
    const float* Wo = W_bil + (size_t)o * WB_OI;

    f32x4 acc[4][4] = {};

    for (int kt = 0; kt < 16; ++kt) {
        const int k0 = kt * 32;
        // A: x2b rows via global_load_lds (2 insts/wave)
        #pragma unroll
        for (int q = 0; q < 2; ++q) {
            const int rb = w * 32 + q * 16;                // wave-uniform
            const int yy = rb + (l >> 2);
            const unsigned short* g = x2b + (size_t)(b * LL + yb + yy) * DD + k0 + (l & 3) * 8;
            load_lds16(g, As + rb * 32);
        }
        // B: W_bil fp32 -> bf16, coalesced dword loads, b64 LDS writes
        #pragma unroll
        for (int p = 0; p < 4; ++p) {
            const int ii = p * 32 + (t >> 3);
            const int j0 = (t & 7) * 4;
            const float* wr = Wo + (size_t)(ib + ii) * 513 + k0 + j0;
            us4 u; u.x = f2bf(wr[0]); u.y = f2bf(wr[1]); u.z = f2bf(wr[2]); u.w = f2bf(wr[3]);
            *(us4*)(Bs + ii * 40 + j0) = u;
        }
        __syncthreads();
        short8 af[4], bf[4];
        const int mrow = wy * 64 + (l & 15);
        const int ncol = wx * 64 + (l & 15);
        const int kg = (l >> 4) * 8;
        #pragma unroll
        for (int mt = 0; mt < 4; ++mt) af[mt] = *(const short8*)(As + (mrow + mt * 16) * 32 + kg);
        #pragma unroll
        for (int nt = 0; nt < 4; ++nt) bf[nt] = *(const short8*)(Bs + (ncol + nt * 16) * 40 + kg);
        #pragma unroll
        for (int mt = 0; mt < 4; ++mt)
            #pragma unroll
            for (int nt = 0; nt < 4; ++nt)
                acc[mt][nt] = __builtin_amdgcn_mfma_f32_16x16x32_bf16(af[mt], bf[nt], acc[mt][nt], 0, 0, 0);
        __syncthreads();
    }

    const float e0 = __expf(bw[0]), e1 = __expf(bw[1]);
    const float bwn0 = e0 / (e0 + e1), bwn1 = e1 / (e0 + e1);
    if (t < 128) {
        const int ig = ib + t;
        corr[t] = bwn1 * W_lin[(size_t)ig * OO + o] + bwn0 * Wo[(size_t)ig * 513 + 512];
    }
    // write raw acc to Cs (bf16), then coalesced transposed store
    #pragma unroll
    for (int mt = 0; mt < 4; ++mt) {
        const int yr = wy * 64 + mt * 16 + ((l >> 4) << 2);
        #pragma unroll
        for (int nt = 0; nt < 4; ++nt) {
            const int ic = wx * 64 + nt * 16 + (l & 15);
            #pragma unroll
            for (int r = 0; r < 4; ++r)
                Cs[(yr + r) * 136 + ic] = f2bf(acc[mt][nt][r]);
        }
    }
    __syncthreads();
    #pragma unroll
    for (int p = 0; p < 8; ++p) {
        const int y  = p * 16 + (t >> 4);
        const int i0 = (t & 15) * 8;
        short8 v = *(const short8*)(Cs + y * 136 + i0);
        us8 uo;
        #pragma unroll
        for (int e = 0; e < 8; ++e) {
            float f = bwn0 * bf2f((unsigned short)v[e]) + corr[i0 + e];
            uo[e] = f2bf(f);
        }
        *(us8*)(Up + ((size_t)(yb + y) * OO + o) * DD + ib + i0) = uo;
    }
}

// ---- pass B: out[b,x,y,:] = x1b @ U'[y]^T + u512[y,:] ----
// grid (x-tile 2, y 256), block 256
__global__ __launch_bounds__(256) void passB_kernel(
    const unsigned short* __restrict__ x1b, const unsigned short* __restrict__ Up,
    const float* __restrict__ u512buf, float* __restrict__ out, int b)
{
    __shared__ unsigned short As[128 * 32];  // [x][i]
    __shared__ unsigned short Bs[128 * 32];  // [o][i]
    __shared__ float u5[128];
    const int t = threadIdx.x, w = t >> 6, l = t & 63;
    const int xb = blockIdx.x * 128;
    const int y  = blockIdx.y;
    const int wy = w & 1, wx = w >> 1;
    if (t < 128) u5[t] = u512buf[y * OO + t];

    f32x4 acc[4][4] = {};

    for (int kt = 0; kt < 16; ++kt) {
        const int k0 = kt * 32;
        #pragma unroll
        for (int q = 0; q < 2; ++q) {
            const int rb = w * 32 + q * 16;
            const int rr = rb + (l >> 2);
            const unsigned short* ga = x1b + (size_t)(b * LL + xb + rr) * DD + k0 + (l & 3) * 8;
            load_lds16(ga, As + rb * 32);
            const unsigned short* gb = Up + (size_t)(y * OO + rr) * DD + k0 + (l & 3) * 8;
            load_lds16(gb, Bs + rb * 32);
        }
        __syncthreads();
        short8 af[4], bf[4];
        const int mrow = wy * 64 + (l & 15);
        const int ncol = wx * 64 + (l & 15);
        const int kg = (l >> 4) * 8;
        #pragma unroll
        for (int mt = 0; mt < 4; ++mt) af[mt] = *(const short8*)(As + (mrow + mt * 16) * 32 + kg);
        #pragma unroll
        for (int nt = 0; nt < 4; ++nt) bf[nt] = *(const short8*)(Bs + (ncol + nt * 16) * 32 + kg);
        #pragma unroll
        for (int mt = 0; mt < 4; ++mt)
            #pragma unroll
            for (int nt = 0; nt < 4; ++nt)
                acc[mt][nt] = __builtin_amdgcn_mfma_f32_16x16x32_bf16(af[mt], bf[nt], acc[mt][nt], 0, 0, 0);
        __syncthreads();
    }

    #pragma unroll
    for (int mt = 0; mt < 4; ++mt) {
        const int xr = wy * 64 + mt * 16 + ((l >> 4) << 2);
        #pragma unroll
        for (int nt = 0; nt < 4; ++nt) {
            const int oc = wx * 64 + nt * 16 + (l & 15);
            const float c = u5[oc];
            #pragma unroll
            for (int r = 0; r < 4; ++r)
                out[((size_t)(b * LL + xb + xr + r) * LL + y) * OO + oc] = acc[mt][nt][r] + c;
        }
    }
}

extern "C" void kernel_launch(void* const* d_in, const int* in_sizes, int n_in,
                              void* d_out, int out_size, void* d_ws, size_t ws_size,
                              hipStream_t stream)
{
    const float* x1    = (const float*)d_in[0];   // [4,256,512]
    const float* x2    = (const float*)d_in[1];   // [4,256,512]
    const float* bw    = (const float*)d_in[2];   // [2]
    const float* W_bil = (const float*)d_in[3];   // [128,513,513]
    const float* W_lin = (const float*)d_in[4];   // [1024,128]
    const float* b_lin = (const float*)d_in[5];   // [128]
    float* out = (float*)d_out;

    char* ws = (char*)d_ws;
    unsigned short* x1b16  = (unsigned short*)ws;                      // 1 MB
    unsigned short* x2b16  = (unsigned short*)(ws + (1u << 20));       // 1 MB
    float*          lin2pb = (float*)(ws + (2u << 20));                // 512 KB
    float*          u512b  = (float*)(ws + (2u << 20) + (512u << 10)); // 128 KB
    unsigned short* Up     = (unsigned short*)(ws + (3u << 20));       // 33.5 MB

    cast_kernel<<<512, 256, 0, stream>>>(x1, x1b16, 131072);
    cast_kernel<<<512, 256, 0, stream>>>(x2, x2b16, 131072);
    lin2_kernel<<<4 * LL, 128, 0, stream>>>(x2, W_lin, b_lin, lin2pb);

    for (int b = 0; b < 4; ++b) {
        u512_kernel<<<LL, 128, 0, stream>>>(x2, W_bil, lin2pb, bw, u512b, b);
        passA_kernel<<<dim3(4, 2, OO), 256, 0, stream>>>(x2b16, W_bil, W_lin, bw, Up, b);
        passB_kernel<<<dim3(2, LL), 256, 0, stream>>>(x1b16, Up, u512b, out, b);
    }
}

// Round 3
// 505.103 us; speedup vs baseline: 6.7708x; 1.2064x over previous
//
#include <hip/hip_runtime.h>

// Biaffine, right-to-left association, MFMA bf16, pre-cast W:
//   Wb16[o,i,j] = bwn0 * W_bil[o,i,j]            (bf16, j<512, prep once)
//   u512[by,o]  = bwn0*(x2b . W_bil[o,512,:]) + bwn1*(x2 . W_lin[512:,o] + b_lin[o])
//   U'[y,o,i]   = (x2b16 @ Wb16[o]^T) + bwn0*W_bil[o,i,512] + bwn1*W_lin[i,o]  (bf16)
//   out[b,x,y,o]= sum_i x1b16[x,i]*U'[y,o,i] + u512[by,o]
// ws: x1b16 1MB | x2b16 1MB | u512 .5MB | Wb16 64MiB | Up 33.5MB  ~= 99 MiB

#define LL 256
#define DD 512
#define OO 128
#define BB 4
#define WB_OI 263169   // 513*513
#define WB_R512 262656 // 512*513

typedef __attribute__((ext_vector_type(8))) short  short8;
typedef __attribute__((ext_vector_type(8))) unsigned short us8;
typedef __attribute__((ext_vector_type(4))) unsigned short us4;
typedef __attribute__((ext_vector_type(4))) float  f32x4;

__device__ __forceinline__ unsigned short f2bf(float f) {
    unsigned int u = __builtin_bit_cast(unsigned int, f);
    u = (u + 0x7FFFu + ((u >> 16) & 1u)) >> 16;
    return (unsigned short)u;
}
__device__ __forceinline__ float bf2f(unsigned short s) {
    return __builtin_bit_cast(float, (unsigned int)s << 16);
}
__device__ __forceinline__ void load_lds16(const void* g, void* l) {
    __builtin_amdgcn_global_load_lds(
        (const __attribute__((address_space(1))) unsigned int*)g,
        (__attribute__((address_space(3))) unsigned int*)l, 16, 0, 0);
}

// ---- cast fp32 -> bf16 (x1, x2) ----
__global__ __launch_bounds__(256) void cast_kernel(
    const float* __restrict__ src, unsigned short* __restrict__ dst, int n4)
{
    int i = blockIdx.x * 256 + threadIdx.x;
    if (i < n4) {
        float4 v = ((const float4*)src)[i];
        us4 u; u.x = f2bf(v.x); u.y = f2bf(v.y); u.z = f2bf(v.z); u.w = f2bf(v.w);
        *(us4*)(dst + (size_t)i * 4) = u;
    }
}

// ---- prep: Wb16[o*512+i][j] = bf16(bwn0 * W_bil[o,i,j]), j<512. 4 rows/block ----
__global__ __launch_bounds__(256) void prepw_kernel(
    const float* __restrict__ Wb, const float* __restrict__ bw,
    unsigned short* __restrict__ Wb16)
{
    const int t = threadIdx.x;
    const int row = blockIdx.x * 4 + (t >> 6);   // o*512 + i
    const int o = row >> 9, i = row & 511;
    const int l = t & 63;
    const float e0 = __expf(bw[0]), e1 = __expf(bw[1]);
    const float bwn0 = e0 / (e0 + e1);
    const float* src = Wb + (size_t)o * WB_OI + (size_t)i * 513 + l * 8;
    float4 v0 = *(const float4*)src;
    float4 v1 = *(const float4*)(src + 4);
    us8 u;
    u[0] = f2bf(bwn0 * v0.x); u[1] = f2bf(bwn0 * v0.y);
    u[2] = f2bf(bwn0 * v0.z); u[3] = f2bf(bwn0 * v0.w);
    u[4] = f2bf(bwn0 * v1.x); u[5] = f2bf(bwn0 * v1.y);
    u[6] = f2bf(bwn0 * v1.z); u[7] = f2bf(bwn0 * v1.w);
    *(us8*)(Wb16 + (size_t)row * 512 + l * 8) = u;
}

// ---- u512[by,o], all batches, linear path folded ----
__global__ __launch_bounds__(128) void u512_kernel(
    const float* __restrict__ x2, const float* __restrict__ Wb,
    const float* __restrict__ W_lin, const float* __restrict__ b_lin,
    const float* __restrict__ bw, float* __restrict__ u512buf)
{
    __shared__ float xs[DD];
    const int by = blockIdx.x;   // 0..1023
    const int o  = threadIdx.x;
    const float* xr = x2 + (size_t)by * DD;
    for (int j = o; j < DD; j += 128) xs[j] = xr[j];
    __syncthreads();
    const float* W2 = Wb + (size_t)o * WB_OI + WB_R512;
    float s1 = W2[512];                 // j=512 (ones col of x2b)
    float s2 = b_lin[o];
    for (int j = 0; j < DD; ++j) {
        s1 += xs[j] * W2[j];
        s2 += xs[j] * W_lin[(size_t)(DD + j) * OO + o];
    }
    const float e0 = __expf(bw[0]), e1 = __expf(bw[1]);
    const float bwn0 = e0 / (e0 + e1), bwn1 = e1 / (e0 + e1);
    u512buf[(size_t)by * OO + o] = bwn0 * s1 + bwn1 * s2;
}

// ---- pass A: U'[y,o,i] = (x2b16 @ Wb16[o]^T) + corr[i]; 128x128 tile, K=512 ----
// grid (4 i-tiles, 2 y-tiles, 128 o), block 256 (2x2 waves)
__global__ __launch_bounds__(256) void passA_kernel(
    const unsigned short* __restrict__ x2b, const unsigned short* __restrict__ Wb16,
    const float* __restrict__ W_bil, const float* __restrict__ W_lin,
    const float* __restrict__ bw, unsigned short* __restrict__ Up, int b)
{
    __shared__ __align__(16) char smem[18432];
    unsigned short* As = (unsigned short*)smem;            // [128 y][32 j] 8KB
    unsigned short* Bs = (unsigned short*)(smem + 8192);   // [128 i][32 j] 8KB
    unsigned short* Cs = (unsigned short*)smem;            // [64][136] 17408B (reuse)
    float* corr = (float*)(smem + 17408);                  // [128]

    const int t = threadIdx.x, w = t >> 6, l = t & 63;
    const int ib = blockIdx.x * 128;
    const int yb = blockIdx.y * 128;
    const int o  = blockIdx.z;
    const int wy = w & 1, wx = w >> 1;

    f32x4 acc[4][4] = {};
    const unsigned short* Wo16 = Wb16 + (size_t)o * DD * DD;

    for (int kt = 0; kt < 16; ++kt) {
        const int k0 = kt * 32;
        #pragma unroll
        for (int q = 0; q < 2; ++q) {
            const int rb = w * 32 + q * 16;                // wave-uniform row base
            const int rr = rb + (l >> 2);
            const int ko = k0 + (l & 3) * 8;
            load_lds16(x2b + (size_t)(b * LL + yb + rr) * DD + ko, As + rb * 32);
            load_lds16(Wo16 + (size_t)(ib + rr) * DD + ko, Bs + rb * 32);
        }
        __syncthreads();
        short8 af[4], bf[4];
        const int mrow = wy * 64 + (l & 15);
        const int ncol = wx * 64 + (l & 15);
        const int kg = (l >> 4) * 8;
        #pragma unroll
        for (int mt = 0; mt < 4; ++mt) af[mt] = *(const short8*)(As + (mrow + mt * 16) * 32 + kg);
        #pragma unroll
        for (int nt = 0; nt < 4; ++nt) bf[nt] = *(const short8*)(Bs + (ncol + nt * 16) * 32 + kg);
        #pragma unroll
        for (int mt = 0; mt < 4; ++mt)
            #pragma unroll
            for (int nt = 0; nt < 4; ++nt)
                acc[mt][nt] = __builtin_amdgcn_mfma_f32_16x16x32_bf16(af[mt], bf[nt], acc[mt][nt], 0, 0, 0);
        __syncthreads();
    }

    const float e0 = __expf(bw[0]), e1 = __expf(bw[1]);
    const float bwn0 = e0 / (e0 + e1), bwn1 = e1 / (e0 + e1);
    if (t < 128) {
        const int ig = ib + t;
        corr[t] = bwn1 * W_lin[(size_t)ig * OO + o]
                + bwn0 * W_bil[(size_t)o * WB_OI + (size_t)ig * 513 + 512];
    }
    // two-half epilogue through 64x136 LDS transpose buffer
    #pragma unroll
    for (int half = 0; half < 2; ++half) {
        if (wy == half) {
            #pragma unroll
            for (int mt = 0; mt < 4; ++mt) {
                const int yl = mt * 16 + ((l >> 4) << 2);   // local row in half
                #pragma unroll
                for (int nt = 0; nt < 4; ++nt) {
                    const int ic = wx * 64 + nt * 16 + (l & 15);
                    #pragma unroll
                    for (int r = 0; r < 4; ++r)
                        Cs[(yl + r) * 136 + ic] = f2bf(acc[mt][nt][r]);
                }
            }
        }
        __syncthreads();
        #pragma unroll
        for (int p = 0; p < 4; ++p) {
            const int yl = p * 16 + (t >> 4);
            const int i0 = (t & 15) * 8;
            short8 v = *(const short8*)(Cs + yl * 136 + i0);
            us8 uo;
            #pragma unroll
            for (int e = 0; e < 8; ++e)
                uo[e] = f2bf(bf2f((unsigned short)v[e]) + corr[i0 + e]);
            *(us8*)(Up + ((size_t)(yb + half * 64 + yl) * OO + o) * DD + ib + i0) = uo;
        }
        __syncthreads();
    }
}

// ---- pass B: out[b,x,y,:] = x1b16 @ U'[y]^T + u512[by,:] ----
// grid (2 x-tiles, 256 y), block 256
__global__ __launch_bounds__(256) void passB_kernel(
    const unsigned short* __restrict__ x1b, const unsigned short* __restrict__ Up,
    const float* __restrict__ u512buf, float* __restrict__ out, int b)
{
    __shared__ unsigned short As[128 * 32];  // [x][i]
    __shared__ unsigned short Bs[128 * 32];  // [o][i]
    __shared__ float u5[128];
    const int t = threadIdx.x, w = t >> 6, l = t & 63;
    const int xb = blockIdx.x * 128;
    const int y  = blockIdx.y;
    const int wy = w & 1, wx = w >> 1;
    if (t < 128) u5[t] = u512buf[(size_t)(b * LL + y) * OO + t];

    f32x4 acc[4][4] = {};

    for (int kt = 0; kt < 16; ++kt) {
        const int k0 = kt * 32;
        #pragma unroll
        for (int q = 0; q < 2; ++q) {
            const int rb = w * 32 + q * 16;
            const int rr = rb + (l >> 2);
            const int ko = k0 + (l & 3) * 8;
            load_lds16(x1b + (size_t)(b * LL + xb + rr) * DD + ko, As + rb * 32);
            load_lds16(Up + (size_t)(y * OO + rr) * DD + ko, Bs + rb * 32);
        }
        __syncthreads();
        short8 af[4], bf[4];
        const int mrow = wy * 64 + (l & 15);
        const int ncol = wx * 64 + (l & 15);
        const int kg = (l >> 4) * 8;
        #pragma unroll
        for (int mt = 0; mt < 4; ++mt) af[mt] = *(const short8*)(As + (mrow + mt * 16) * 32 + kg);
        #pragma unroll
        for (int nt = 0; nt < 4; ++nt) bf[nt] = *(const short8*)(Bs + (ncol + nt * 16) * 32 + kg);
        #pragma unroll
        for (int mt = 0; mt < 4; ++mt)
            #pragma unroll
            for (int nt = 0; nt < 4; ++nt)
                acc[mt][nt] = __builtin_amdgcn_mfma_f32_16x16x32_bf16(af[mt], bf[nt], acc[mt][nt], 0, 0, 0);
        __syncthreads();
    }

    #pragma unroll
    for (int mt = 0; mt < 4; ++mt) {
        const int xr = wy * 64 + mt * 16 + ((l >> 4) << 2);
        #pragma unroll
        for (int nt = 0; nt < 4; ++nt) {
            const int oc = wx * 64 + nt * 16 + (l & 15);
            const float c = u5[oc];
            #pragma unroll
            for (int r = 0; r < 4; ++r)
                out[((size_t)(b * LL + xb + xr + r) * LL + y) * OO + oc] = acc[mt][nt][r] + c;
        }
    }
}

extern "C" void kernel_launch(void* const* d_in, const int* in_sizes, int n_in,
                              void* d_out, int out_size, void* d_ws, size_t ws_size,
                              hipStream_t stream)
{
    const float* x1    = (const float*)d_in[0];
    const float* x2    = (const float*)d_in[1];
    const float* bw    = (const float*)d_in[2];
    const float* W_bil = (const float*)d_in[3];
    const float* W_lin = (const float*)d_in[4];
    const float* b_lin = (const float*)d_in[5];
    float* out = (float*)d_out;

    char* ws = (char*)d_ws;
    unsigned short* x1b16 = (unsigned short*)ws;                       // 1 MB
    unsigned short* x2b16 = (unsigned short*)(ws + (1u << 20));        // 1 MB
    float*          u512b = (float*)(ws + (2u << 20));                 // 512 KB
    unsigned short* Wb16  = (unsigned short*)(ws + (3u << 20));        // 64 MiB
    unsigned short* Up    = (unsigned short*)(ws + (3u << 20) + ((size_t)128 * 512 * 512 * 2)); // 33.5 MB

    cast_kernel<<<512, 256, 0, stream>>>(x1, x1b16, 131072);
    cast_kernel<<<512, 256, 0, stream>>>(x2, x2b16, 131072);
    prepw_kernel<<<16384, 256, 0, stream>>>(W_bil, bw, Wb16);
    u512_kernel<<<BB * LL, 128, 0, stream>>>(x2, W_bil, W_lin, b_lin, bw, u512b);

    for (int b = 0; b < BB; ++b) {
        passA_kernel<<<dim3(4, 2, OO), 256, 0, stream>>>(x2b16, Wb16, W_bil, W_lin, bw, Up, b);
        passB_kernel<<<dim3(2, LL), 256, 0, stream>>>(x1b16, Up, u512b, out, b);
    }
}